// Round 12
// baseline (403.096 us; speedup 1.0000x reference)
//
#include <hip/hip_runtime.h>

// LSTM T=1024, B=2048, INPUT=2, H=64 — MFMA recurrence.
// R11: ONE 512-thread block per CU-pair... no: 256 blocks x 8 waves (512 thr),
// BB=8, 2 waves/SIMD. Wave w: slice sl=w&3 (h-rows [16sl,16sl+16)), batch
// half bh=w>>2 (batches 4bh..4bh+3, 4x column-dup, 1 state/lane).
// Per-wave VALU ~250 cyc (R10 cuts: zero-C MFMA, post-select gx, paired rcp,
// single b16 h-write - no pack), so per-SIMD VALU stays ~500 while the twin
// waves hide each other's MFMA block + ds_read + trans latency (m114).
// One shared barrier + h-table (vs R7's two blocks - its failure mode was
// +40% VALU/SIMD). Numerics: bf16 W_hh, bf16 h, fp32 c (absmax 4.88e-4).

typedef short bf16x8 __attribute__((ext_vector_type(8)));
typedef float f32x4  __attribute__((ext_vector_type(4)));

constexpr int T_STEPS = 1024;
constexpr int BATCH   = 2048;
constexpr int H       = 64;
constexpr int BB      = 8;      // batch per block (2 halves x 4)
constexpr int THREADS = 512;    // 8 waves
constexpr int HSTR    = 80;     // bf16 per batch row (160 B = 40 dwords)

__device__ __forceinline__ unsigned bf16_rn(float f) {
    unsigned u = __float_as_uint(f);
    u += 0x7fffu + ((u >> 16) & 1u);
    return u >> 16;
}
__device__ __forceinline__ float rcp_(float v)  { return __builtin_amdgcn_rcpf(v); }
__device__ __forceinline__ float exp2_(float v) { return __builtin_amdgcn_exp2f(v); }
// barrier that does NOT drain vmcnt (keeps x prefetch in flight)
__device__ __forceinline__ void lds_barrier() {
    asm volatile("s_waitcnt lgkmcnt(0)" ::: "memory");
    __builtin_amdgcn_s_barrier();
}

__global__ __launch_bounds__(THREADS, 1) void lstm_mfma11(
    const float* __restrict__ x,      // (T, B, 2)
    const float* __restrict__ W_ih,   // (256, 2)
    const float* __restrict__ W_hh,   // (256, 64)
    const float* __restrict__ b_ih,   // (256)
    const float* __restrict__ b_hh,   // (256)
    const float* __restrict__ W_fc,   // (1, 64)
    const float* __restrict__ b_fc,   // (1)
    float* __restrict__ out)          // (B, 1)
{
    const int tid  = threadIdx.x;
    const int w    = tid >> 6;        // wave 0..7
    const int sl   = w & 3;           // h-slice: rows [16sl, 16sl+16)
    const int bh   = w >> 2;          // batch half: batches 4bh..4bh+3
    const int lane = tid & 63;
    const int bcol = lane & 15;       // MFMA column
    const int grp  = lane >> 4;       // k-group / D-row group
    const int bloc = bcol & 3;        // real batch in half (cols 4..15 dup)
    const int eh   = bcol >> 2;       // which D element this lane activates
    const int bb   = 4 * bh + bloc;   // batch index within block

    __shared__ __align__(16) unsigned short s_ht[2][BB * HSTR]; // 2 x 1280 B
    __shared__ float s_red[8][4];

    const int b0 = blockIdx.x * BB;

    // ---- A fragments: gate g tile = W_hh rows [64g+16sl, +16), single bf16
    bf16x8 Af[4][2];
    #pragma unroll
    for (int g = 0; g < 4; ++g) {
        #pragma unroll
        for (int kk = 0; kk < 2; ++kk) {
            const float* src = W_hh + (64 * g + 16 * sl + bcol) * H + kk * 32 + grp * 8;
            #pragma unroll
            for (int j = 0; j < 8; ++j)
                Af[g][kk][j] = (short)bf16_rn(src[j]);
        }
    }

    // ---- per-lane single state: h-row rbase of batch b0+bb ---------------
    const int rbase = 16 * sl + 4 * grp + eh;
    float cs = 0.f, hv = 0.f;
    const float wfc = W_fc[rbase];

    // ---- gx constants ONLY for the 4 used (gate) rows --------------------
    float gbs[4], c0s[4], c1s[4];
    #pragma unroll
    for (int g = 0; g < 4; ++g) {
        const int r = 64 * g + rbase;
        gbs[g] = b_ih[r] + b_hh[r];
        c0s[g] = W_ih[2 * r];
        c1s[g] = W_ih[2 * r + 1];
    }

    // hoisted zero C for the first MFMA of each chain
    const f32x4 zero4 = {0.f, 0.f, 0.f, 0.f};

    // zero both h-table buffers (2*8*80 shorts = 640 dwords)
    for (int i = tid; i < 640; i += THREADS)
        reinterpret_cast<unsigned*>(s_ht)[i] = 0;

    // ---- x: depth-3 register prefetch (dup lanes load same addr) ----------
    const float* xb = x + (b0 + bb) * 2;
    float2 xc  = *reinterpret_cast<const float2*>(xb);
    float2 xn1 = *reinterpret_cast<const float2*>(xb + 1 * BATCH * 2);
    float2 xn2 = *reinterpret_cast<const float2*>(xb + 2 * BATCH * 2);

    __syncthreads();   // full barrier once (init visible)

    // initial B fragments from buf 0 (h = 0); single b128 per kk
    bf16x8 Bf[2];
    #pragma unroll
    for (int kk = 0; kk < 2; ++kk)
        Bf[kk] = *reinterpret_cast<const bf16x8*>(
                     &s_ht[0][bb * HSTR + kk * 32 + grp * 8]);

    constexpr float L1 = -1.44269504f;   // -log2(e)
    constexpr float L2 =  2.88539008f;   //  2 log2(e)

    #pragma unroll 2
    for (int s = 0; s < T_STEPS; ++s) {
        // issue next x load FIRST (completes ~3 steps later; never drained)
        const int sn = (s + 3 < T_STEPS) ? s + 3 : T_STEPS - 1;
        const float2 xf = *reinterpret_cast<const float2*>(xb + sn * BATCH * 2);

        // recurrent GEMM: 4 gate-chains of 2 dependent MFMAs, C = zero
        f32x4 acc[4];
        #pragma unroll
        for (int g = 0; g < 4; ++g)
            acc[g] = __builtin_amdgcn_mfma_f32_16x16x32_bf16(Af[g][0], Bf[0], zero4, 0, 0, 0);
        #pragma unroll
        for (int g = 0; g < 4; ++g)
            acc[g] = __builtin_amdgcn_mfma_f32_16x16x32_bf16(Af[g][1], Bf[1], acc[g], 0, 0, 0);

        // select this lane's single state + add gx (4 used cells)
        float p[4];
        #pragma unroll
        for (int g = 0; g < 4; ++g) {
            const float v01 = (eh & 1) ? acc[g][1] : acc[g][0];
            const float v23 = (eh & 1) ? acc[g][3] : acc[g][2];
            const float sel = (eh & 2) ? v23 : v01;
            p[g] = sel + fmaf(c1s[g], xc.y, fmaf(c0s[g], xc.x, gbs[g]));
        }

        // activations with paired reciprocals (3 rcp + 5 exp2 per state)
        {
            const float ei = exp2_(p[0] * L1), ef = exp2_(p[1] * L1);
            const float eg = exp2_(p[2] * L2), eo = exp2_(p[3] * L1);
            const float ai = 1.f + ei, af = 1.f + ef;
            const float ag = 1.f + eg, ao = 1.f + eo;
            const float rif = rcp_(ai * af);            // 1/((1+ei)(1+ef))
            const float si = rif * af, sf = rif * ai;   // sigm(i), sigm(f)
            const float rgo = rcp_(ag * ao);
            const float tg = fmaf(-2.f, rgo * ao, 1.f); // tanh(g)
            const float so = rgo * ag;                  // sigm(o)
            cs = fmaf(sf, cs, si * tg);
            const float ec = exp2_(cs * L2);
            hv = so * fmaf(-2.f, rcp_(1.f + ec), 1.f);
        }

        // single b16 h-write (no pack), next-parity table
        s_ht[(s + 1) & 1][bb * HSTR + rbase] = (unsigned short)bf16_rn(hv);

        // rotate x prefetch (depth 3)
        xc = xn1; xn1 = xn2; xn2 = xf;

        lds_barrier();   // lgkmcnt(0) + s_barrier; vmem stays in flight

        // B fragments for next step: b128 quads tile banks exactly 2-way
        #pragma unroll
        for (int kk = 0; kk < 2; ++kk)
            Bf[kk] = *reinterpret_cast<const bf16x8*>(
                         &s_ht[(s + 1) & 1][bb * HSTR + kk * 32 + grp * 8]);
    }

    // ---- fused fc epilogue ----------------------------------------------
    float v = hv * wfc;
    v += __shfl_xor(v, 4);    // eh bit 0
    v += __shfl_xor(v, 8);    // eh bit 1
    v += __shfl_xor(v, 16);   // grp bit 0
    v += __shfl_xor(v, 32);   // grp bit 1
    if (lane < 4) s_red[w][lane] = v;   // per-wave partial for its 4 batches
    __syncthreads();
    if (tid < BB) {
        const int tbh = tid >> 2, tbl = tid & 3;
        out[b0 + tid] = s_red[4 * tbh + 0][tbl] + s_red[4 * tbh + 1][tbl]
                      + s_red[4 * tbh + 2][tbl] + s_red[4 * tbh + 3][tbl]
                      + b_fc[0];
    }
}

extern "C" void kernel_launch(void* const* d_in, const int* in_sizes, int n_in,
                              void* d_out, int out_size, void* d_ws, size_t ws_size,
                              hipStream_t stream) {
    const float* x    = (const float*)d_in[0];
    const float* W_ih = (const float*)d_in[1];
    const float* W_hh = (const float*)d_in[2];
    const float* b_ih = (const float*)d_in[3];
    const float* b_hh = (const float*)d_in[4];
    const float* W_fc = (const float*)d_in[5];
    const float* b_fc = (const float*)d_in[6];
    float* out = (float*)d_out;

    dim3 grid(BATCH / BB);   // 256 blocks -> all 256 CUs
    dim3 block(THREADS);     // 8 waves = 2 per SIMD
    lstm_mfma11<<<grid, block, 0, stream>>>(x, W_ih, W_hh, b_ih, b_hh, W_fc, b_fc, out);
}

// Round 13
// 359.071 us; speedup vs baseline: 1.1226x; 1.1226x over previous
//
#include <hip/hip_runtime.h>

// LSTM T=1024, B=2048, INPUT=2, H=64 — MFMA recurrence.
// R12: forced-ANTIPHASE twin blocks. BB=4, 512 blocks -> 2 independent
// blocks/CU (2 waves/SIMD, separate barriers). Lean body (zero-C MFMA,
// post-select gx on 4 cells, paired rcp, single b16 h-write, 1 state/lane).
// Blocks with (blockIdx & 256) spin ~512 cyc once at start: under sequential
// dispatch those are each CU's SECOND block, so the two co-resident blocks
// run half-period skewed -> block A's MFMA/LDS phase overlaps block B's
// VALU phase (separate pipes). R7/R11 showed in-phase twins serialize
// (1190/1050 cyc); R10's single wave leaves pipes idle in turn (930 cyc).
// Numerics: bf16 W_hh, fresh-rounded bf16 h, fp32 c (absmax 4.88e-4).

typedef short bf16x8 __attribute__((ext_vector_type(8)));
typedef float f32x4  __attribute__((ext_vector_type(4)));

constexpr int T_STEPS = 1024;
constexpr int BATCH   = 2048;
constexpr int H       = 64;
constexpr int BB      = 4;      // batch per block
constexpr int THREADS = 256;    // 4 waves
constexpr int HSTR    = 80;     // bf16 per batch row (160 B = 40 dwords)

__device__ __forceinline__ unsigned bf16_rn(float f) {
    unsigned u = __float_as_uint(f);
    u += 0x7fffu + ((u >> 16) & 1u);
    return u >> 16;
}
__device__ __forceinline__ float rcp_(float v)  { return __builtin_amdgcn_rcpf(v); }
__device__ __forceinline__ float exp2_(float v) { return __builtin_amdgcn_exp2f(v); }
// barrier that does NOT drain vmcnt (keeps x prefetch in flight)
__device__ __forceinline__ void lds_barrier() {
    asm volatile("s_waitcnt lgkmcnt(0)" ::: "memory");
    __builtin_amdgcn_s_barrier();
}

__global__ __launch_bounds__(THREADS, 2) void lstm_mfma12(
    const float* __restrict__ x,      // (T, B, 2)
    const float* __restrict__ W_ih,   // (256, 2)
    const float* __restrict__ W_hh,   // (256, 64)
    const float* __restrict__ b_ih,   // (256)
    const float* __restrict__ b_hh,   // (256)
    const float* __restrict__ W_fc,   // (1, 64)
    const float* __restrict__ b_fc,   // (1)
    float* __restrict__ out)          // (B, 1)
{
    const int tid  = threadIdx.x;
    const int w    = tid >> 6;        // wave 0..3: h-slice [16w, 16w+16)
    const int lane = tid & 63;
    const int bcol = lane & 15;       // MFMA column
    const int grp  = lane >> 4;       // k-group / D-row group
    const int bloc = bcol & 3;        // real batch (cols 4..15 dup 0..3)
    const int eh   = bcol >> 2;       // which D element this lane activates

    __shared__ __align__(16) unsigned short s_ht[2][BB * HSTR]; // 2 x 640 B
    __shared__ float s_red[16];

    const int b0 = blockIdx.x * BB;

    // ---- A fragments: gate g tile = W_hh rows [64g+16w, +16), single bf16 -
    bf16x8 Af[4][2];
    #pragma unroll
    for (int g = 0; g < 4; ++g) {
        #pragma unroll
        for (int kk = 0; kk < 2; ++kk) {
            const float* src = W_hh + (64 * g + 16 * w + bcol) * H + kk * 32 + grp * 8;
            #pragma unroll
            for (int j = 0; j < 8; ++j)
                Af[g][kk][j] = (short)bf16_rn(src[j]);
        }
    }

    // ---- per-lane single state: h-row rbase of batch b0+bloc --------------
    const int rbase = 16 * w + 4 * grp + eh;
    float cs = 0.f, hv = 0.f;
    const float wfc = W_fc[rbase];

    // ---- gx constants ONLY for the 4 used (gate) rows ---------------------
    float gbs[4], c0s[4], c1s[4];
    #pragma unroll
    for (int g = 0; g < 4; ++g) {
        const int r = 64 * g + rbase;
        gbs[g] = b_ih[r] + b_hh[r];
        c0s[g] = W_ih[2 * r];
        c1s[g] = W_ih[2 * r + 1];
    }

    // hoisted zero C for the first MFMA of each chain
    const f32x4 zero4 = {0.f, 0.f, 0.f, 0.f};

    // zero both h-table buffers (2*4*80 shorts = 320 dwords)
    for (int i = tid; i < 320; i += THREADS)
        reinterpret_cast<unsigned*>(s_ht)[i] = 0;

    // ---- x: depth-3 register prefetch (dup lanes load same addr) ----------
    const float* xb = x + (b0 + bloc) * 2;
    float2 xc  = *reinterpret_cast<const float2*>(xb);
    float2 xn1 = *reinterpret_cast<const float2*>(xb + 1 * BATCH * 2);
    float2 xn2 = *reinterpret_cast<const float2*>(xb + 2 * BATCH * 2);

    __syncthreads();   // one full barrier (init visible)

    // ---- ANTIPHASE SKEW: second dispatch wave spins ~512 cyc once ---------
    if (blockIdx.x & 256) {
        asm volatile(
            "s_nop 7\n s_nop 7\n s_nop 7\n s_nop 7\n s_nop 7\n s_nop 7\n s_nop 7\n s_nop 7\n"
            "s_nop 7\n s_nop 7\n s_nop 7\n s_nop 7\n s_nop 7\n s_nop 7\n s_nop 7\n s_nop 7\n"
            "s_nop 7\n s_nop 7\n s_nop 7\n s_nop 7\n s_nop 7\n s_nop 7\n s_nop 7\n s_nop 7\n"
            "s_nop 7\n s_nop 7\n s_nop 7\n s_nop 7\n s_nop 7\n s_nop 7\n s_nop 7\n s_nop 7\n"
            "s_nop 7\n s_nop 7\n s_nop 7\n s_nop 7\n s_nop 7\n s_nop 7\n s_nop 7\n s_nop 7\n"
            "s_nop 7\n s_nop 7\n s_nop 7\n s_nop 7\n s_nop 7\n s_nop 7\n s_nop 7\n s_nop 7\n"
            "s_nop 7\n s_nop 7\n s_nop 7\n s_nop 7\n s_nop 7\n s_nop 7\n s_nop 7\n s_nop 7\n"
            "s_nop 7\n s_nop 7\n s_nop 7\n s_nop 7\n s_nop 7\n s_nop 7\n s_nop 7\n s_nop 7\n"
            ::: "memory");
    }

    // initial B fragments from buf 0 (h = 0); single b128 per kk
    bf16x8 Bf[2];
    #pragma unroll
    for (int kk = 0; kk < 2; ++kk)
        Bf[kk] = *reinterpret_cast<const bf16x8*>(
                     &s_ht[0][bloc * HSTR + kk * 32 + grp * 8]);

    constexpr float L1 = -1.44269504f;   // -log2(e)
    constexpr float L2 =  2.88539008f;   //  2 log2(e)

    #pragma unroll 2
    for (int s = 0; s < T_STEPS; ++s) {
        // issue next x load FIRST (completes ~3 steps later; never drained)
        const int sn = (s + 3 < T_STEPS) ? s + 3 : T_STEPS - 1;
        const float2 xf = *reinterpret_cast<const float2*>(xb + sn * BATCH * 2);

        // recurrent GEMM: 4 gate-chains of 2 dependent MFMAs, C = zero
        f32x4 acc[4];
        #pragma unroll
        for (int g = 0; g < 4; ++g)
            acc[g] = __builtin_amdgcn_mfma_f32_16x16x32_bf16(Af[g][0], Bf[0], zero4, 0, 0, 0);
        #pragma unroll
        for (int g = 0; g < 4; ++g)
            acc[g] = __builtin_amdgcn_mfma_f32_16x16x32_bf16(Af[g][1], Bf[1], acc[g], 0, 0, 0);

        // select this lane's single state + add gx (4 used cells)
        float p[4];
        #pragma unroll
        for (int g = 0; g < 4; ++g) {
            const float v01 = (eh & 1) ? acc[g][1] : acc[g][0];
            const float v23 = (eh & 1) ? acc[g][3] : acc[g][2];
            const float sel = (eh & 2) ? v23 : v01;
            p[g] = sel + fmaf(c1s[g], xc.y, fmaf(c0s[g], xc.x, gbs[g]));
        }

        // activations with paired reciprocals (5 exp2 + 3 rcp)
        {
            const float ei = exp2_(p[0] * L1), ef = exp2_(p[1] * L1);
            const float eg = exp2_(p[2] * L2), eo = exp2_(p[3] * L1);
            const float ai = 1.f + ei, af = 1.f + ef;
            const float ag = 1.f + eg, ao = 1.f + eo;
            const float rif = rcp_(ai * af);            // 1/((1+ei)(1+ef))
            const float si = rif * af, sf = rif * ai;   // sigm(i), sigm(f)
            const float rgo = rcp_(ag * ao);
            const float tg = fmaf(-2.f, rgo * ao, 1.f); // tanh(g)
            const float so = rgo * ag;                  // sigm(o)
            cs = fmaf(sf, cs, si * tg);
            const float ec = exp2_(cs * L2);
            hv = so * fmaf(-2.f, rcp_(1.f + ec), 1.f);
        }

        // single b16 h-write (no pack), next-parity table
        s_ht[(s + 1) & 1][bloc * HSTR + rbase] = (unsigned short)bf16_rn(hv);

        // rotate x prefetch (depth 3)
        xc = xn1; xn1 = xn2; xn2 = xf;

        lds_barrier();   // lgkmcnt(0) + s_barrier; vmem stays in flight

        // B fragments for next step: b128 quads tile banks <=2-way (free)
        #pragma unroll
        for (int kk = 0; kk < 2; ++kk)
            Bf[kk] = *reinterpret_cast<const bf16x8*>(
                         &s_ht[(s + 1) & 1][bloc * HSTR + kk * 32 + grp * 8]);
    }

    // ---- fused fc epilogue ----------------------------------------------
    float v = hv * wfc;
    v += __shfl_xor(v, 4);    // eh bit 0
    v += __shfl_xor(v, 8);    // eh bit 1
    v += __shfl_xor(v, 16);   // grp bit 0
    v += __shfl_xor(v, 32);   // grp bit 1
    if (lane < 4) s_red[w * 4 + lane] = v;   // one writer per (w, bloc)
    __syncthreads();
    if (tid < 4) {
        out[b0 + tid] = s_red[tid] + s_red[4 + tid] + s_red[8 + tid]
                      + s_red[12 + tid] + b_fc[0];
    }
}

extern "C" void kernel_launch(void* const* d_in, const int* in_sizes, int n_in,
                              void* d_out, int out_size, void* d_ws, size_t ws_size,
                              hipStream_t stream) {
    const float* x    = (const float*)d_in[0];
    const float* W_ih = (const float*)d_in[1];
    const float* W_hh = (const float*)d_in[2];
    const float* b_ih = (const float*)d_in[3];
    const float* b_hh = (const float*)d_in[4];
    const float* W_fc = (const float*)d_in[5];
    const float* b_fc = (const float*)d_in[6];
    float* out = (float*)d_out;

    dim3 grid(BATCH / BB);   // 512 blocks -> 2 independent blocks per CU
    dim3 block(THREADS);     // 4 waves
    lstm_mfma12<<<grid, block, 0, stream>>>(x, W_ih, W_hh, b_ih, b_hh, W_fc, b_fc, out);
}

// Round 14
// 336.266 us; speedup vs baseline: 1.1987x; 1.0678x over previous
//
#include <hip/hip_runtime.h>

// LSTM T=1024, B=2048, INPUT=2, H=64 — MFMA recurrence.
// R13 = R12 (antiphase twin blocks: BB=4, 512 blocks = 2 independent
// blocks/CU, lean 1-state/lane body, zero-C MFMA, paired rcp, lds_barrier,
// ~512cyc startup skew for the second dispatch half) + VALU-issue cuts:
//  - log2e folded into gx constants: pL = fmaf(sel, Lg, gxL) with gxL
//    computed from pre-scaled c0L/c1L/gbL -> 3 ops/gate (was 4).
//  - gxL computed textually BEFORE the MFMA block (issues in MFMA shadow).
//  - unroll 4 (static parity addresses, more scheduling freedom).
// Rationale: R10 vs R12 decomposition shows we are ~82% VALU-issue-bound;
// per-wave VALU cuts are 2x-leveraged (both antiphase waves pay them).
// Numerics: bf16 W_hh, fresh-rounded bf16 h, fp32 c (absmax ~4.9e-4).

typedef short bf16x8 __attribute__((ext_vector_type(8)));
typedef float f32x4  __attribute__((ext_vector_type(4)));

constexpr int T_STEPS = 1024;
constexpr int BATCH   = 2048;
constexpr int H       = 64;
constexpr int BB      = 4;      // batch per block
constexpr int THREADS = 256;    // 4 waves
constexpr int HSTR    = 80;     // bf16 per batch row (160 B = 40 dwords)

__device__ __forceinline__ unsigned bf16_rn(float f) {
    unsigned u = __float_as_uint(f);
    u += 0x7fffu + ((u >> 16) & 1u);
    return u >> 16;
}
__device__ __forceinline__ float rcp_(float v)  { return __builtin_amdgcn_rcpf(v); }
__device__ __forceinline__ float exp2_(float v) { return __builtin_amdgcn_exp2f(v); }
// barrier that does NOT drain vmcnt (keeps x prefetch in flight)
__device__ __forceinline__ void lds_barrier() {
    asm volatile("s_waitcnt lgkmcnt(0)" ::: "memory");
    __builtin_amdgcn_s_barrier();
}

__global__ __launch_bounds__(THREADS, 2) void lstm_mfma13(
    const float* __restrict__ x,      // (T, B, 2)
    const float* __restrict__ W_ih,   // (256, 2)
    const float* __restrict__ W_hh,   // (256, 64)
    const float* __restrict__ b_ih,   // (256)
    const float* __restrict__ b_hh,   // (256)
    const float* __restrict__ W_fc,   // (1, 64)
    const float* __restrict__ b_fc,   // (1)
    float* __restrict__ out)          // (B, 1)
{
    const int tid  = threadIdx.x;
    const int w    = tid >> 6;        // wave 0..3: h-slice [16w, 16w+16)
    const int lane = tid & 63;
    const int bcol = lane & 15;       // MFMA column
    const int grp  = lane >> 4;       // k-group / D-row group
    const int bloc = bcol & 3;        // real batch (cols 4..15 dup 0..3)
    const int eh   = bcol >> 2;       // which D element this lane activates

    __shared__ __align__(16) unsigned short s_ht[2][BB * HSTR]; // 2 x 640 B
    __shared__ float s_red[16];

    const int b0 = blockIdx.x * BB;

    constexpr float L1 = -1.44269504f;   // -log2(e)
    constexpr float L2 =  2.88539008f;   //  2 log2(e)

    // ---- A fragments: gate g tile = W_hh rows [64g+16w, +16), single bf16 -
    bf16x8 Af[4][2];
    #pragma unroll
    for (int g = 0; g < 4; ++g) {
        #pragma unroll
        for (int kk = 0; kk < 2; ++kk) {
            const float* src = W_hh + (64 * g + 16 * w + bcol) * H + kk * 32 + grp * 8;
            #pragma unroll
            for (int j = 0; j < 8; ++j)
                Af[g][kk][j] = (short)bf16_rn(src[j]);
        }
    }

    // ---- per-lane single state: h-row rbase of batch b0+bloc --------------
    const int rbase = 16 * w + 4 * grp + eh;
    float cs = 0.f, hv = 0.f;
    const float wfc = W_fc[rbase];

    // ---- gx constants for the 4 used rows, PRE-SCALED by Lg ---------------
    // gate 0,1,3 (i,f,o): scale L1; gate 2 (g): scale L2.
    float gbL[4], c0L[4], c1L[4];
    #pragma unroll
    for (int g = 0; g < 4; ++g) {
        const int r = 64 * g + rbase;
        const float Lg = (g == 2) ? L2 : L1;
        gbL[g] = (b_ih[r] + b_hh[r]) * Lg;
        c0L[g] = W_ih[2 * r] * Lg;
        c1L[g] = W_ih[2 * r + 1] * Lg;
    }

    // hoisted zero C for the first MFMA of each chain
    const f32x4 zero4 = {0.f, 0.f, 0.f, 0.f};

    // zero both h-table buffers (2*4*80 shorts = 320 dwords)
    for (int i = tid; i < 320; i += THREADS)
        reinterpret_cast<unsigned*>(s_ht)[i] = 0;

    // ---- x: depth-3 register prefetch (dup lanes load same addr) ----------
    const float* xb = x + (b0 + bloc) * 2;
    float2 xc  = *reinterpret_cast<const float2*>(xb);
    float2 xn1 = *reinterpret_cast<const float2*>(xb + 1 * BATCH * 2);
    float2 xn2 = *reinterpret_cast<const float2*>(xb + 2 * BATCH * 2);

    __syncthreads();   // one full barrier (init visible)

    // ---- ANTIPHASE SKEW: second dispatch wave spins ~512 cyc once ---------
    if (blockIdx.x & 256) {
        asm volatile(
            "s_nop 7\n s_nop 7\n s_nop 7\n s_nop 7\n s_nop 7\n s_nop 7\n s_nop 7\n s_nop 7\n"
            "s_nop 7\n s_nop 7\n s_nop 7\n s_nop 7\n s_nop 7\n s_nop 7\n s_nop 7\n s_nop 7\n"
            "s_nop 7\n s_nop 7\n s_nop 7\n s_nop 7\n s_nop 7\n s_nop 7\n s_nop 7\n s_nop 7\n"
            "s_nop 7\n s_nop 7\n s_nop 7\n s_nop 7\n s_nop 7\n s_nop 7\n s_nop 7\n s_nop 7\n"
            "s_nop 7\n s_nop 7\n s_nop 7\n s_nop 7\n s_nop 7\n s_nop 7\n s_nop 7\n s_nop 7\n"
            "s_nop 7\n s_nop 7\n s_nop 7\n s_nop 7\n s_nop 7\n s_nop 7\n s_nop 7\n s_nop 7\n"
            "s_nop 7\n s_nop 7\n s_nop 7\n s_nop 7\n s_nop 7\n s_nop 7\n s_nop 7\n s_nop 7\n"
            "s_nop 7\n s_nop 7\n s_nop 7\n s_nop 7\n s_nop 7\n s_nop 7\n s_nop 7\n s_nop 7\n"
            ::: "memory");
    }

    // initial B fragments from buf 0 (h = 0); single b128 per kk
    bf16x8 Bf[2];
    #pragma unroll
    for (int kk = 0; kk < 2; ++kk)
        Bf[kk] = *reinterpret_cast<const bf16x8*>(
                     &s_ht[0][bloc * HSTR + kk * 32 + grp * 8]);

    #pragma unroll 4
    for (int s = 0; s < T_STEPS; ++s) {
        // issue next x load FIRST (completes ~3 steps later; never drained)
        const int sn = (s + 3 < T_STEPS) ? s + 3 : T_STEPS - 1;
        const float2 xf = *reinterpret_cast<const float2*>(xb + sn * BATCH * 2);

        // gxL for this step (depends only on xc) — issues in the MFMA shadow
        float gxL[4];
        #pragma unroll
        for (int g = 0; g < 4; ++g)
            gxL[g] = fmaf(c1L[g], xc.y, fmaf(c0L[g], xc.x, gbL[g]));

        // recurrent GEMM: 4 gate-chains of 2 dependent MFMAs, C = zero
        f32x4 acc[4];
        #pragma unroll
        for (int g = 0; g < 4; ++g)
            acc[g] = __builtin_amdgcn_mfma_f32_16x16x32_bf16(Af[g][0], Bf[0], zero4, 0, 0, 0);
        #pragma unroll
        for (int g = 0; g < 4; ++g)
            acc[g] = __builtin_amdgcn_mfma_f32_16x16x32_bf16(Af[g][1], Bf[1], acc[g], 0, 0, 0);

        // select this lane's single state, fold Lg scale + gxL in one fma
        float pL[4];
        #pragma unroll
        for (int g = 0; g < 4; ++g) {
            const float v01 = (eh & 1) ? acc[g][1] : acc[g][0];
            const float v23 = (eh & 1) ? acc[g][3] : acc[g][2];
            const float sel = (eh & 2) ? v23 : v01;
            pL[g] = fmaf(sel, (g == 2) ? L2 : L1, gxL[g]);
        }

        // activations with paired reciprocals (5 exp2 + 3 rcp)
        {
            const float ei = exp2_(pL[0]), ef = exp2_(pL[1]);
            const float eg = exp2_(pL[2]), eo = exp2_(pL[3]);
            const float ai = 1.f + ei, af = 1.f + ef;
            const float ag = 1.f + eg, ao = 1.f + eo;
            const float rif = rcp_(ai * af);            // 1/((1+ei)(1+ef))
            const float si = rif * af, sf = rif * ai;   // sigm(i), sigm(f)
            const float rgo = rcp_(ag * ao);
            const float tg = fmaf(-2.f, rgo * ao, 1.f); // tanh(g)
            const float so = rgo * ag;                  // sigm(o)
            cs = fmaf(sf, cs, si * tg);
            const float ec = exp2_(cs * L2);
            hv = so * fmaf(-2.f, rcp_(1.f + ec), 1.f);
        }

        // single b16 h-write (no pack), next-parity table
        s_ht[(s + 1) & 1][bloc * HSTR + rbase] = (unsigned short)bf16_rn(hv);

        // rotate x prefetch (depth 3)
        xc = xn1; xn1 = xn2; xn2 = xf;

        lds_barrier();   // lgkmcnt(0) + s_barrier; vmem stays in flight

        // B fragments for next step: b128 quads tile banks <=2-way (free)
        #pragma unroll
        for (int kk = 0; kk < 2; ++kk)
            Bf[kk] = *reinterpret_cast<const bf16x8*>(
                         &s_ht[(s + 1) & 1][bloc * HSTR + kk * 32 + grp * 8]);
    }

    // ---- fused fc epilogue ----------------------------------------------
    float v = hv * wfc;
    v += __shfl_xor(v, 4);    // eh bit 0
    v += __shfl_xor(v, 8);    // eh bit 1
    v += __shfl_xor(v, 16);   // grp bit 0
    v += __shfl_xor(v, 32);   // grp bit 1
    if (lane < 4) s_red[w * 4 + lane] = v;   // one writer per (w, bloc)
    __syncthreads();
    if (tid < 4) {
        out[b0 + tid] = s_red[tid] + s_red[4 + tid] + s_red[8 + tid]
                      + s_red[12 + tid] + b_fc[0];
    }
}

extern "C" void kernel_launch(void* const* d_in, const int* in_sizes, int n_in,
                              void* d_out, int out_size, void* d_ws, size_t ws_size,
                              hipStream_t stream) {
    const float* x    = (const float*)d_in[0];
    const float* W_ih = (const float*)d_in[1];
    const float* W_hh = (const float*)d_in[2];
    const float* b_ih = (const float*)d_in[3];
    const float* b_hh = (const float*)d_in[4];
    const float* W_fc = (const float*)d_in[5];
    const float* b_fc = (const float*)d_in[6];
    float* out = (float*)d_out;

    dim3 grid(BATCH / BB);   // 512 blocks -> 2 independent blocks per CU
    dim3 block(THREADS);     // 4 waves
    lstm_mfma13<<<grid, block, 0, stream>>>(x, W_ih, W_hh, b_ih, b_hh, W_fc, b_fc, out);
}